// Round 7
// baseline (573.802 us; speedup 1.0000x reference)
//
#include <hip/hip_runtime.h>
#include <hip/hip_cooperative_groups.h>
#include <math.h>

namespace cg = cooperative_groups;

#define BN   32
#define CN   256
#define HN   56
#define WN   56
#define HWN  (HN * WN)          // 3136
#define HW4  (HWN / 4)          // 784 quads per spatial plane
#define CHW4 (CN * HW4)         // 200704 quads per batch
#define CHWN (CN * HWN)         // 802816
#define NPOS (BN * HWN)         // 100352
#define NQ   (NPOS / 4)         // 25088 quads
#define GRID 784                // NQ / 32 (exact)

typedef float f32x4 __attribute__((ext_vector_type(4)));

// Single cooperative kernel, 784 blocks x 256 threads (4 waves).
// __launch_bounds__(256,4): 4 blocks/CU guaranteed -> 1024 slots >= 784,
// cooperative co-residency holds (VGPR capped at 128, kernel needs ~48;
// LDS 4KB/block).
//
// Phase 1 (reduce): block owns a 32-quad (512B) span of output positions.
//   4 waves x 2 half-waves split the 256 channels (c = w*64 + sub + 2k);
//   every load instruction fetches 2 aligned 512B-contiguous fragments.
//   8 partials per quad combined through LDS.
// Phase 2 (conv+sigmoid): block b handles positions [128b, 128b+128) --
//   halo rows come from neighbor blocks via L2/L3; threadfence+grid.sync
//   makes them visible across XCDs.
// Phase 3 (multiply): block re-reads THE SAME 128KB of x it read in phase 1
//   (identical xbase addressing) -> L2/L3 hits instead of HBM. out via
//   nt-store (never re-read; don't evict x from the caches mid-stream).
__global__ __launch_bounds__(256, 4) void sa_fused_kernel(
    const f32x4* __restrict__ x4,
    const float* __restrict__ cw,
    f32x4*       __restrict__ out4,
    float*       __restrict__ avg,
    float*       __restrict__ mx,
    float*       __restrict__ att)
{
    __shared__ f32x4 s_sum[8][32];
    __shared__ f32x4 s_max[8][32];

    int t    = threadIdx.x;
    int lane = t & 63;
    int w    = t >> 6;        // wave 0..3
    int j    = lane & 31;     // quad within block's 32-quad span
    int sub  = lane >> 5;     // channel parity within wave

    int q  = blockIdx.x * 32 + j;   // global position-quad
    int b  = q / HW4;
    int s4 = q - b * HW4;
    size_t xbase = (size_t)b * CHW4 + (size_t)(w * 64 + sub) * HW4 + s4;

    // ---------------- phase 1: channel-wise mean & max ----------------
    f32x4 sum = {0.0f, 0.0f, 0.0f, 0.0f};
    f32x4 m   = {-INFINITY, -INFINITY, -INFINITY, -INFINITY};
#pragma unroll 8
    for (int k = 0; k < 32; ++k) {            // channels w*64 + sub + 2k
        f32x4 v = x4[xbase + (size_t)(2 * k) * HW4];
        sum += v;
        m.x = fmaxf(m.x, v.x);
        m.y = fmaxf(m.y, v.y);
        m.z = fmaxf(m.z, v.z);
        m.w = fmaxf(m.w, v.w);
    }
    s_sum[w * 2 + sub][j] = sum;
    s_max[w * 2 + sub][j] = m;
    __syncthreads();

    if (t < 32) {
        f32x4 sa = s_sum[0][t];
        f32x4 ma = s_max[0][t];
#pragma unroll
        for (int p = 1; p < 8; ++p) {
            sa += s_sum[p][t];
            f32x4 mp = s_max[p][t];
            ma.x = fmaxf(ma.x, mp.x);
            ma.y = fmaxf(ma.y, mp.y);
            ma.z = fmaxf(ma.z, mp.z);
            ma.w = fmaxf(ma.w, mp.w);
        }
        int qq = blockIdx.x * 32 + t;
        ((f32x4*)avg)[qq] = sa * (1.0f / (float)CN);
        ((f32x4*)mx)[qq]  = ma;
    }
    __threadfence();            // push avg/mx past L2 (cross-XCD visibility)
    cg::this_grid().sync();

    // ---------------- phase 2: 7x7 conv + sigmoid ----------------
    if (t < 128) {
        int p  = blockIdx.x * 128 + t;        // 784*128 == NPOS exactly
        int bb = p / HWN;
        int s  = p - bb * HWN;
        int h  = s / WN;
        int w0 = s - h * WN;
        const float* a0 = avg + bb * HWN;
        const float* m0 = mx + bb * HWN;
        float acc = 0.0f;
#pragma unroll
        for (int kh = 0; kh < 7; ++kh) {
            int hh = h + kh - 3;
            if (hh < 0 || hh >= HN) continue;
#pragma unroll
            for (int kw = 0; kw < 7; ++kw) {
                int ww = w0 + kw - 3;
                if (ww < 0 || ww >= WN) continue;
                int idx = hh * WN + ww;
                acc = fmaf(cw[kh * 7 + kw],      a0[idx], acc);
                acc = fmaf(cw[49 + kh * 7 + kw], m0[idx], acc);
            }
        }
        att[p] = 1.0f / (1.0f + expf(-acc));
    }
    __threadfence();
    cg::this_grid().sync();

    // ---------------- phase 3: out = x * att ----------------
    f32x4 a = ((const f32x4*)att)[q];         // one att quad per lane, reused 64x
#pragma unroll 8
    for (int k = 0; k < 32; ++k) {
        size_t gi = xbase + (size_t)(2 * k) * HW4;   // same bytes as phase 1
        f32x4 v = x4[gi];
        v.x *= a.x;
        v.y *= a.y;
        v.z *= a.z;
        v.w *= a.w;
        __builtin_nontemporal_store(v, out4 + gi);
    }
}

extern "C" void kernel_launch(void* const* d_in, const int* in_sizes, int n_in,
                              void* d_out, int out_size, void* d_ws, size_t ws_size,
                              hipStream_t stream) {
    const f32x4* x4  = (const f32x4*)d_in[0];
    const float* cw  = (const float*)d_in[1];
    f32x4* out4      = (f32x4*)d_out;

    float* avg = (float*)d_ws;          // NPOS floats
    float* mx  = avg + NPOS;            // NPOS floats
    float* att = mx + NPOS;             // NPOS floats (16B-aligned: NPOS*4 % 16 == 0)

    void* args[] = { (void*)&x4, (void*)&cw, (void*)&out4,
                     (void*)&avg, (void*)&mx, (void*)&att };
    hipLaunchCooperativeKernel((void*)sa_fused_kernel,
                               dim3(GRID), dim3(256), args, 0, stream);
}

// Round 8
// 204.814 us; speedup vs baseline: 2.8016x; 2.8016x over previous
//
#include <hip/hip_runtime.h>
#include <math.h>

#define BN   32
#define CN   256
#define HN   56
#define WN   56
#define HWN  (HN * WN)          // 3136
#define HW4  (HWN / 4)          // 784 quads per spatial plane
#define CHW4 (CN * HW4)         // 200704 quads per batch
#define NPOS (BN * HWN)         // 100352
#define NQ   (NPOS / 4)         // 25088 position-quads
#define SPAN 64                 // quads per block (1KB span)
#define NBLK (NQ / SPAN)        // 392 (exact)

typedef float f32x4 __attribute__((ext_vector_type(4)));

// NOTE (r7 lesson): cooperative grid.sync costs ~150-200us per sync on this
// chip (784-block coop kernel: 437us for ~60us of work, VALUBusy 0.8%).
// Never fuse via grid sync here. But r7 also proved x stays L3-resident
// across the whole op (FETCH=102MB for 206MB of reads) -> kernel 3's x read
// is an L3 hit as long as we use plain caching loads.

// Kernel 1: channel-wise mean & max.
// 392 blocks x 512 threads. Block owns a 64-quad (1KB) span of positions;
// wave w reduces channels [w*32, w*32+32) for the whole span. Every load
// instruction fetches 1KB CONTIGUOUS from a single channel (vs r5's 2x512B
// from 2 channels) -> max DRAM row locality. 8 partials/quad via LDS.
// 3136 waves (12.25/CU), unroll 8 -> ~8KB in flight/wave (~98KB/CU vs
// ~9KB Little's-law need).
__global__ __launch_bounds__(512) void sa_reduce_kernel(const f32x4* __restrict__ x4,
                                                        f32x4* __restrict__ avg4,
                                                        f32x4* __restrict__ mx4) {
    __shared__ f32x4 s_sum[8][SPAN];
    __shared__ f32x4 s_max[8][SPAN];

    int t = threadIdx.x;
    int j = t & 63;               // quad within block span (lane)
    int w = t >> 6;               // wave 0..7 -> channel chunk

    int q  = blockIdx.x * SPAN + j;   // global position-quad
    int b  = q / HW4;                 // per-lane: span may straddle batches
    int s4 = q - b * HW4;
    const f32x4* xp = x4 + (size_t)b * CHW4 + (size_t)(w * 32) * HW4 + s4;

    f32x4 sum = {0.0f, 0.0f, 0.0f, 0.0f};
    f32x4 m   = {-INFINITY, -INFINITY, -INFINITY, -INFINITY};
#pragma unroll 8
    for (int k = 0; k < 32; ++k) {        // channels w*32+k
        f32x4 v = xp[(size_t)k * HW4];
        sum += v;
        m.x = fmaxf(m.x, v.x);
        m.y = fmaxf(m.y, v.y);
        m.z = fmaxf(m.z, v.z);
        m.w = fmaxf(m.w, v.w);
    }
    s_sum[w][j] = sum;
    s_max[w][j] = m;
    __syncthreads();

    if (t < SPAN) {
        f32x4 sa = s_sum[0][t];
        f32x4 ma = s_max[0][t];
#pragma unroll
        for (int p = 1; p < 8; ++p) {
            sa += s_sum[p][t];
            f32x4 mp = s_max[p][t];
            ma.x = fmaxf(ma.x, mp.x);
            ma.y = fmaxf(ma.y, mp.y);
            ma.z = fmaxf(ma.z, mp.z);
            ma.w = fmaxf(ma.w, mp.w);
        }
        int qq = blockIdx.x * SPAN + t;
        avg4[qq] = sa * (1.0f / (float)CN);
        mx4[qq]  = ma;
    }
}

// Kernel 2: 7x7 conv over the 2-channel (avg,max) map + sigmoid -> att.
// 0.8MB inputs, L2-resident, ~4us. Unchanged.
__global__ __launch_bounds__(256) void sa_conv_kernel(const float* __restrict__ avg,
                                                      const float* __restrict__ mx,
                                                      const float* __restrict__ cw,
                                                      float* __restrict__ att) {
    int p = blockIdx.x * blockDim.x + threadIdx.x;
    if (p >= NPOS) return;
    int b = p / HWN;
    int s = p - b * HWN;
    int h = s / WN;
    int w = s - h * WN;
    const float* a0 = avg + b * HWN;
    const float* m0 = mx + b * HWN;
    float acc = 0.0f;
#pragma unroll
    for (int kh = 0; kh < 7; ++kh) {
        int hh = h + kh - 3;
        if (hh < 0 || hh >= HN) continue;
#pragma unroll
        for (int kw = 0; kw < 7; ++kw) {
            int ww = w + kw - 3;
            if (ww < 0 || ww >= WN) continue;
            int idx = hh * WN + ww;
            acc = fmaf(cw[kh * 7 + kw],      a0[idx], acc);
            acc = fmaf(cw[49 + kh * 7 + kw], m0[idx], acc);
        }
    }
    att[p] = 1.0f / (1.0f + expf(-acc));
}

// Kernel 3: out = x * att. MIRRORS kernel 1's addressing exactly (same
// 392-block, 64-quad-span, 32-channels-per-wave geometry): 1KB contiguous
// per load/store instruction, att staged once in LDS and register-held.
// x via plain load (L3-resident per r7 evidence); out via nt-store (never
// re-read; don't evict x mid-stream). 8-deep unroll -> fewer, fatter blocks
// vs r5's 25088 one-load blocks.
__global__ __launch_bounds__(512) void sa_mul_kernel(const f32x4* __restrict__ x4,
                                                     const f32x4* __restrict__ att4,
                                                     f32x4* __restrict__ out4) {
    __shared__ f32x4 s_att[SPAN];
    int t = threadIdx.x;
    int j = t & 63;
    int w = t >> 6;

    if (t < SPAN) s_att[t] = att4[blockIdx.x * SPAN + t];
    __syncthreads();

    int q  = blockIdx.x * SPAN + j;
    int b  = q / HW4;
    int s4 = q - b * HW4;
    size_t base = (size_t)b * CHW4 + (size_t)(w * 32) * HW4 + s4;

    f32x4 a = s_att[j];
#pragma unroll 8
    for (int k = 0; k < 32; ++k) {
        size_t gi = base + (size_t)k * HW4;
        f32x4 v = x4[gi];
        v.x *= a.x;
        v.y *= a.y;
        v.z *= a.z;
        v.w *= a.w;
        __builtin_nontemporal_store(v, out4 + gi);
    }
}

extern "C" void kernel_launch(void* const* d_in, const int* in_sizes, int n_in,
                              void* d_out, int out_size, void* d_ws, size_t ws_size,
                              hipStream_t stream) {
    const float* x  = (const float*)d_in[0];
    const float* cw = (const float*)d_in[1];
    float* out = (float*)d_out;

    float* avg = (float*)d_ws;          // NPOS floats (16B-aligned)
    float* mx  = avg + NPOS;
    float* att = mx + NPOS;

    sa_reduce_kernel<<<NBLK, 512, 0, stream>>>(
        (const f32x4*)x, (f32x4*)avg, (f32x4*)mx);

    sa_conv_kernel<<<(NPOS + 255) / 256, 256, 0, stream>>>(avg, mx, cw, att);

    sa_mul_kernel<<<NBLK, 512, 0, stream>>>(
        (const f32x4*)x, (const f32x4*)att, (f32x4*)out);
}